// Round 2
// baseline (251.321 us; speedup 1.0000x reference)
//
#include <hip/hip_runtime.h>

// (32, 3, 384, 640) fp32 in, (32, 1, 384, 640) fp32 out.
#define BATCH 32
#define CHAN  3
#define HH    384
#define WW    640
#define TW 4     // pixels per thread, x
#define TH 8     // pixels per thread, y
#define BX 32    // threads x  -> block covers 128 px wide
#define BY 8     // threads y  -> block covers 64 px tall

__device__ __forceinline__ int reflectW(int v) {
    if (v < 0) v = -v;
    if (v >= WW) v = 2 * WW - 2 - v;
    return v;
}
__device__ __forceinline__ int reflectH(int v) {
    if (v < 0) v = -v;
    if (v >= HH) v = 2 * HH - 2 - v;
    return v;
}

__global__ __launch_bounds__(BX * BY)
void ssim_l1_kernel(const float* __restrict__ src,
                    const float* __restrict__ tgt,
                    float* __restrict__ out) {
    const int w0 = (blockIdx.x * BX + threadIdx.x) * TW;
    const int h0 = (blockIdx.y * BY + threadIdx.y) * TH;
    const int b  = blockIdx.z;

    const int wm1 = reflectW(w0 - 1);
    const int wp4 = reflectW(w0 + TW);

    const float inv9  = 1.0f / 9.0f;
    const float C1v   = 6.5025f;     // (0.01*255)^2
    const float C2v   = 58.5225f;    // (0.03*255)^2
    const float wssim = 0.5f * 0.85f / 3.0f;
    const float wl1   = 0.15f / 3.0f;

    float acc[TH][TW];
#pragma unroll
    for (int r = 0; r < TH; r++)
#pragma unroll
        for (int k = 0; k < TW; k++) acc[r][k] = 0.0f;

#pragma unroll
    for (int c = 0; c < CHAN; c++) {
        const float* __restrict__ xs = src + (size_t)(b * CHAN + c) * (HH * WW);
        const float* __restrict__ ys = tgt + (size_t)(b * CHAN + c) * (HH * WW);

        // 3-row ring of horizontal 3-sums for the 5 box quantities,
        // plus center |x-y| for the L1 term.
        float hx[3][TW], hy[3][TW], hxx[3][TW], hyy[3][TW], hxy[3][TW];
        float dab[3][TW];

        auto load_row = [&](int hr, int slot) {
            const float* __restrict__ xr = xs + hr * WW;
            const float* __restrict__ yr = ys + hr * WW;
            float4 xv = *(const float4*)(xr + w0);
            float4 yv = *(const float4*)(yr + w0);
            float x[6], y[6];
            x[0] = xr[wm1]; x[1] = xv.x; x[2] = xv.y; x[3] = xv.z; x[4] = xv.w; x[5] = xr[wp4];
            y[0] = yr[wm1]; y[1] = yv.x; y[2] = yv.y; y[3] = yv.z; y[4] = yv.w; y[5] = yr[wp4];
            float xx[6], yy[6], xy[6];
#pragma unroll
            for (int i = 0; i < 6; i++) {
                xx[i] = x[i] * x[i];
                yy[i] = y[i] * y[i];
                xy[i] = x[i] * y[i];
            }
#pragma unroll
            for (int k = 0; k < TW; k++) {
                hx [slot][k] = x [k] + x [k + 1] + x [k + 2];
                hy [slot][k] = y [k] + y [k + 1] + y [k + 2];
                hxx[slot][k] = xx[k] + xx[k + 1] + xx[k + 2];
                hyy[slot][k] = yy[k] + yy[k + 1] + yy[k + 2];
                hxy[slot][k] = xy[k] + xy[k + 1] + xy[k + 2];
                dab[slot][k] = fabsf(x[k + 1] - y[k + 1]);
            }
        };

        // prologue: rows h0-1 and h0 into slots 0,1
        load_row(reflectH(h0 - 1), 0);
        load_row(h0, 1);

#pragma unroll
        for (int r = 0; r < TH; r++) {
            const int snew = (r + 2) % 3;   // row h0+r+1
            const int scen = (r + 1) % 3;   // row h0+r (center)
            load_row(reflectH(h0 + r + 1), snew);
#pragma unroll
            for (int k = 0; k < TW; k++) {
                float Sx  = hx [0][k] + hx [1][k] + hx [2][k];
                float Sy  = hy [0][k] + hy [1][k] + hy [2][k];
                float Sxx = hxx[0][k] + hxx[1][k] + hxx[2][k];
                float Syy = hyy[0][k] + hyy[1][k] + hyy[2][k];
                float Sxy = hxy[0][k] + hxy[1][k] + hxy[2][k];

                float mux = Sx * inv9;
                float muy = Sy * inv9;
                float sigx  = fmaf(Sxx, inv9, -mux);          // faithful: -mu, not -mu^2
                float sigy  = fmaf(Syy, inv9, -muy);
                float mm    = mux * muy;
                float sigxy = fmaf(Sxy, inv9, -mm);

                float num = fmaf(2.0f, mm, C1v) * fmaf(2.0f, sigxy, C2v);
                float den = fmaf(muy, muy, fmaf(mux, mux, C1v)) * (sigx + sigy + C2v);
                float q   = num * __builtin_amdgcn_rcpf(den);
                float ns  = fmaf(q, -0.5f, 0.5f);
                ns = fminf(fmaxf(ns, 0.0f), 1.0f);

                acc[r][k] = fmaf(wssim, ns, fmaf(wl1, dab[scen][k], acc[r][k]));
            }
        }
    }

#pragma unroll
    for (int r = 0; r < TH; r++) {
        float4 o = make_float4(acc[r][0], acc[r][1], acc[r][2], acc[r][3]);
        *(float4*)(out + ((size_t)b * HH + (h0 + r)) * WW + w0) = o;
    }
}

extern "C" void kernel_launch(void* const* d_in, const int* in_sizes, int n_in,
                              void* d_out, int out_size, void* d_ws, size_t ws_size,
                              hipStream_t stream) {
    const float* src = (const float*)d_in[0];   // 'output'
    const float* tgt = (const float*)d_in[1];   // 'target'
    float* out = (float*)d_out;

    dim3 grid(WW / (BX * TW), HH / (BY * TH), BATCH);   // (5, 6, 32)
    dim3 block(BX, BY);
    ssim_l1_kernel<<<grid, block, 0, stream>>>(src, tgt, out);
}